// Round 1
// baseline (665.324 us; speedup 1.0000x reference)
//
#include <hip/hip_runtime.h>

// ---- types ----
typedef _Float16 f16;
typedef _Float16 f16x8 __attribute__((ext_vector_type(8)));
typedef _Float16 f16x4 __attribute__((ext_vector_type(4)));
typedef float    f32x4 __attribute__((ext_vector_type(4)));

// ---- problem constants ----
constexpr int NB   = 8;      // batch
constexpr int T    = 2048;   // Tx = Tz
constexpr int D    = 1024;   // Dx = Dz = Datt = Dout
constexpr int NTRI = 136;    // 16*17/2 causal blocks per batch (128x128 blocks)

// =====================================================================
// Weight cast + transpose: W[k][n] fp32 -> Wt[n][k] f16   (3 matrices)
// =====================================================================
__global__ __launch_bounds__(256) void cast_transpose_w(
    const float* __restrict__ W0, const float* __restrict__ W1,
    const float* __restrict__ W2, f16* __restrict__ Wt)
{
    __shared__ f16 tile[32][33];
    const int which = blockIdx.z;
    const float* W = which == 0 ? W0 : (which == 1 ? W1 : W2);
    f16* dst = Wt + (size_t)which * D * D;
    const int c0 = blockIdx.x * 32, r0 = blockIdx.y * 32;
    const int tx = threadIdx.x & 31, ty = threadIdx.x >> 5;   // ty: 0..7
    #pragma unroll
    for (int i = 0; i < 32; i += 8)
        tile[ty + i][tx] = (f16)W[(size_t)(r0 + ty + i) * D + c0 + tx];
    __syncthreads();
    #pragma unroll
    for (int i = 0; i < 32; i += 8)
        dst[(size_t)(c0 + ty + i) * D + r0 + tx] = tile[tx][ty + i];
}

// =====================================================================
// V transpose: V[b][t][o] f16 -> Vt[b][o][t] f16
// =====================================================================
__global__ __launch_bounds__(256) void transpose_v(
    const f16* __restrict__ V, f16* __restrict__ Vt)
{
    __shared__ f16 tile[32][33];
    const int b = blockIdx.z;
    const f16* src = V  + (size_t)b * T * D;
    f16*       dst = Vt + (size_t)b * D * T;
    const int c0 = blockIdx.x * 32, r0 = blockIdx.y * 32;   // c over D, r over T
    const int tx = threadIdx.x & 31, ty = threadIdx.x >> 5;
    #pragma unroll
    for (int i = 0; i < 32; i += 8)
        tile[ty + i][tx] = src[(size_t)(r0 + ty + i) * D + c0 + tx];
    __syncthreads();
    #pragma unroll
    for (int i = 0; i < 32; i += 8)
        dst[(size_t)(c0 + ty + i) * T + r0 + tx] = tile[tx][ty + i];
}

// =====================================================================
// NT GEMM, 128x128 tile, BK=32, 256 threads (4 waves, each 64x64).
// C = A @ B^T where B is stored [N][K] row-major (K contiguous) -> both
// operands load 8 contiguous k per lane (MFMA 16x16x32 f16 fragments).
// MODE 0: QKV   A fp32 [16384][1024] (cvt->f16 in staging), B=Wt, +bias, C f16
// MODE 1: S     A=Q f16, B=K f16 (per batch), causal packed fp32 out, *1/32
// MODE 2: PV    A=Amat f16 [T][T], B=Vt f16 [D][T], K clipped causal, C fp32
// =====================================================================
template<int MODE>
__global__ __launch_bounds__(256) void gemm_nt(
    const void* __restrict__ Ag_, const f16* __restrict__ Bg_,
    void* __restrict__ Cg_, const float* __restrict__ bias)
{
    __shared__ f16 As[128 * 32];
    __shared__ f16 Bs[128 * 32];

    const int bx = blockIdx.x, by = blockIdx.y, bz = blockIdx.z;
    if (MODE == 1 && bx > by) return;   // causal: j-block > i-block -> skip

    const float* Af = nullptr;
    const f16*   Ah = nullptr;
    const f16*   Bg = Bg_;
    int lda, ldb, K;
    const size_t bm0 = (size_t)by * 128, bn0 = (size_t)bx * 128;

    if (MODE == 0)      { Af = (const float*)Ag_;                    lda = D; ldb = D; K = D; }
    else if (MODE == 1) { Ah = (const f16*)Ag_ + (size_t)bz * T * D; lda = D;
                          Bg = Bg_ + (size_t)bz * T * D;             ldb = D; K = D; }
    else                { Ah = (const f16*)Ag_ + (size_t)bz * T * T; lda = T;
                          Bg = Bg_ + (size_t)bz * D * T;             ldb = T;
                          K  = (by + 1) * 128; }                     // causal K clip

    const int t    = threadIdx.x;
    const int lane = t & 63, wave = t >> 6;
    const int wr   = (wave >> 1) * 64, wc = (wave & 1) * 64;

    f32x4 acc[4][4] = {};

    for (int k0 = 0; k0 < K; k0 += 32) {
        // ---- stage A tile [128][32] ----
        if (MODE == 0) {
            const int r = t >> 3, kc = (t & 7) * 4;
            #pragma unroll
            for (int it = 0; it < 4; ++it) {
                const float4 v = *(const float4*)(Af + (bm0 + r + it * 32) * lda + k0 + kc);
                f16x4 u = { (f16)v.x, (f16)v.y, (f16)v.z, (f16)v.w };
                *(f16x4*)&As[(r + it * 32) * 32 + kc] = u;
            }
        } else {
            const int r = t >> 2, kc = (t & 3) * 8;
            #pragma unroll
            for (int it = 0; it < 2; ++it)
                *(int4*)&As[(r + it * 64) * 32 + kc] =
                    *(const int4*)(Ah + (bm0 + r + it * 64) * lda + k0 + kc);
        }
        // ---- stage B tile [128][32] (always f16) ----
        {
            const int r = t >> 2, kc = (t & 3) * 8;
            #pragma unroll
            for (int it = 0; it < 2; ++it)
                *(int4*)&Bs[(r + it * 64) * 32 + kc] =
                    *(const int4*)(Bg + (bn0 + r + it * 64) * ldb + k0 + kc);
        }
        __syncthreads();

        // ---- fragments + MFMA ----
        f16x8 av[4], bvv[4];
        const int fr = lane & 15, fo = (lane >> 4) * 8;
        #pragma unroll
        for (int i = 0; i < 4; ++i)
            av[i] = *(const f16x8*)&As[(wr + i * 16 + fr) * 32 + fo];
        #pragma unroll
        for (int j = 0; j < 4; ++j)
            bvv[j] = *(const f16x8*)&Bs[(wc + j * 16 + fr) * 32 + fo];
        #pragma unroll
        for (int i = 0; i < 4; ++i)
            #pragma unroll
            for (int j = 0; j < 4; ++j)
                acc[i][j] = __builtin_amdgcn_mfma_f32_16x16x32_f16(av[i], bvv[j], acc[i][j], 0, 0, 0);
        __syncthreads();
    }

    // ---- epilogue.  C/D lane map: col = lane&15, row = (lane>>4)*4 + reg ----
    const int cr = (lane >> 4) * 4, cc = lane & 15;
    if (MODE == 0) {
        f16* Cp = (f16*)Cg_;
        #pragma unroll
        for (int j = 0; j < 4; ++j) {
            const int col = (int)bn0 + wc + j * 16 + cc;
            const float bb = bias[col];
            #pragma unroll
            for (int i = 0; i < 4; ++i)
                #pragma unroll
                for (int g = 0; g < 4; ++g)
                    Cp[(bm0 + wr + i * 16 + cr + g) * D + col] = (f16)(acc[i][j][g] + bb);
        }
    } else if (MODE == 1) {
        float* Cp = (float*)Cg_ + ((size_t)bz * NTRI + (size_t)by * (by + 1) / 2 + bx) * 16384;
        #pragma unroll
        for (int i = 0; i < 4; ++i)
            #pragma unroll
            for (int j = 0; j < 4; ++j)
                #pragma unroll
                for (int g = 0; g < 4; ++g) {
                    const int lr = wr + i * 16 + cr + g, lc = wc + j * 16 + cc;
                    const int gr = by * 128 + lr, gc = bx * 128 + lc;
                    Cp[lr * 128 + lc] = (gc > gr) ? -3.0e38f : acc[i][j][g] * 0.03125f;
                }
    } else {
        float* Cp = (float*)Cg_ + (size_t)bz * T * D;
        #pragma unroll
        for (int i = 0; i < 4; ++i)
            #pragma unroll
            for (int j = 0; j < 4; ++j)
                #pragma unroll
                for (int g = 0; g < 4; ++g)
                    Cp[(bm0 + wr + i * 16 + cr + g) * D + bn0 + wc + j * 16 + cc] = acc[i][j][g];
    }
}

// =====================================================================
// Row softmax over packed causal S.  One block per (row, batch).
// Reads len = ceil128(r+1) fp32 logits, writes A[r][0..len) f16.
// (PV clips its K loop to exactly len, so j>=len is never read.)
// =====================================================================
__global__ __launch_bounds__(256) void softmax_rows(
    const float* __restrict__ Sp, f16* __restrict__ Am)
{
    const int r = blockIdx.x, b = blockIdx.y;
    const int ib  = r >> 7;
    const int len = (ib + 1) << 7;
    const float* Sbase = Sp + ((size_t)b * NTRI + (size_t)ib * (ib + 1) / 2) * 16384
                            + (size_t)(r & 127) * 128;
    const int t = threadIdx.x;

    float vals[8];
    float m = -3.4e38f;
    #pragma unroll
    for (int i = 0; i < 8; ++i) {
        const int j = t + i * 256;
        const float v = (j < len) ? Sbase[(size_t)(j >> 7) * 16384 + (j & 127)] : -3.4e38f;
        vals[i] = v;
        m = fmaxf(m, v);
    }
    #pragma unroll
    for (int o = 32; o > 0; o >>= 1) m = fmaxf(m, __shfl_xor(m, o, 64));
    __shared__ float red[4];
    if ((t & 63) == 0) red[t >> 6] = m;
    __syncthreads();
    m = fmaxf(fmaxf(red[0], red[1]), fmaxf(red[2], red[3]));
    __syncthreads();

    float s = 0.f;
    #pragma unroll
    for (int i = 0; i < 8; ++i) {
        const float e = __expf(vals[i] - m);   // OOB/masked -> exp(-huge) = 0
        vals[i] = e;
        s += e;
    }
    #pragma unroll
    for (int o = 32; o > 0; o >>= 1) s += __shfl_xor(s, o, 64);
    if ((t & 63) == 0) red[t >> 6] = s;
    __syncthreads();
    s = (red[0] + red[1]) + (red[2] + red[3]);
    const float rinv = 1.0f / s;

    f16* Arow = Am + (size_t)b * T * T + (size_t)r * T;
    #pragma unroll
    for (int i = 0; i < 8; ++i) {
        const int j = t + i * 256;
        if (j < len) Arow[j] = (f16)(vals[i] * rinv);
    }
}

// =====================================================================
// launch
// =====================================================================
extern "C" void kernel_launch(void* const* d_in, const int* in_sizes, int n_in,
                              void* d_out, int out_size, void* d_ws, size_t ws_size,
                              hipStream_t stream)
{
    const float* x  = (const float*)d_in[0];
    const float* z  = (const float*)d_in[1];
    const float* Wq = (const float*)d_in[2];
    const float* bq = (const float*)d_in[3];
    const float* Wk = (const float*)d_in[4];
    const float* bk = (const float*)d_in[5];
    const float* Wv = (const float*)d_in[6];
    const float* bv = (const float*)d_in[7];
    // d_in[8] = mask: fixed causal lower-triangular, baked into the kernels.
    float* out = (float*)d_out;

    char* ws = (char*)d_ws;
    // ws layout (bytes):
    //   Wt  @ 0          :  6 MiB  (3 x 1024x1024 f16, transposed)
    //   Qh  @ 6291456    : 32 MiB
    //   Kh  @ 39845888   : 32 MiB
    //   Vh  @ 73400320   : 32 MiB
    //   Vt  @ 106954752  : 32 MiB
    //   Sp  @ 140509184  : 68 MiB  (packed causal fp32 blocks)
    //   Am  @ 6291456    : 64 MiB  (overlaps Qh+Kh, dead after gemm_s)
    f16*   Wt = (f16*)(ws);
    f16*   Qh = (f16*)(ws + 6291456ull);
    f16*   Kh = (f16*)(ws + 39845888ull);
    f16*   Vh = (f16*)(ws + 73400320ull);
    f16*   Vt = (f16*)(ws + 106954752ull);
    float* Sp = (float*)(ws + 140509184ull);
    f16*   Am = (f16*)(ws + 6291456ull);

    cast_transpose_w<<<dim3(32, 32, 3), 256, 0, stream>>>(Wq, Wk, Wv, Wt);
    gemm_nt<0><<<dim3(8, 128, 1), 256, 0, stream>>>(x, Wt,           Qh, bq);
    gemm_nt<0><<<dim3(8, 128, 1), 256, 0, stream>>>(z, Wt + 1048576, Kh, bk);
    gemm_nt<0><<<dim3(8, 128, 1), 256, 0, stream>>>(z, Wt + 2097152, Vh, bv);
    transpose_v<<<dim3(32, 64, 8), 256, 0, stream>>>(Vh, Vt);
    gemm_nt<1><<<dim3(16, 16, 8), 256, 0, stream>>>(Qh, Kh, Sp, nullptr);
    softmax_rows<<<dim3(2048, 8, 1), 256, 0, stream>>>(Sp, Am);
    gemm_nt<2><<<dim3(8, 16, 8), 256, 0, stream>>>(Am, Vt, out, nullptr);
}

// Round 2
// 534.764 us; speedup vs baseline: 1.2441x; 1.2441x over previous
//
#include <hip/hip_runtime.h>

// ---- types ----
typedef _Float16 f16;
typedef _Float16 f16x8 __attribute__((ext_vector_type(8)));
typedef _Float16 f16x4 __attribute__((ext_vector_type(4)));
typedef float    f32x4 __attribute__((ext_vector_type(4)));

// ---- problem constants ----
constexpr int NB   = 8;      // batch
constexpr int T    = 2048;   // Tx = Tz
constexpr int D    = 1024;   // Dx = Dz = Datt = Dout
constexpr int NTRI = 136;    // 16*17/2 causal 128x128 blocks per batch

// async global->LDS, 16B per lane; LDS dest = wave-uniform base + lane*16
__device__ __forceinline__ void load_lds16(const f16* g, f16* l) {
    __builtin_amdgcn_global_load_lds(
        (const __attribute__((address_space(1))) void*)g,
        (__attribute__((address_space(3))) void*)l, 16, 0, 0);
}

// =====================================================================
// Weight cast + transpose: W[k][n] fp32 -> Wt[n][k] f16   (3 matrices)
// =====================================================================
__global__ __launch_bounds__(256) void cast_transpose_w(
    const float* __restrict__ W0, const float* __restrict__ W1,
    const float* __restrict__ W2, f16* __restrict__ Wt)
{
    __shared__ f16 tile[32][33];
    const int which = blockIdx.z;
    const float* W = which == 0 ? W0 : (which == 1 ? W1 : W2);
    f16* dst = Wt + (size_t)which * D * D;
    const int c0 = blockIdx.x * 32, r0 = blockIdx.y * 32;
    const int tx = threadIdx.x & 31, ty = threadIdx.x >> 5;   // ty: 0..7
    #pragma unroll
    for (int i = 0; i < 32; i += 8)
        tile[ty + i][tx] = (f16)W[(size_t)(r0 + ty + i) * D + c0 + tx];
    __syncthreads();
    #pragma unroll
    for (int i = 0; i < 32; i += 8)
        dst[(size_t)(c0 + ty + i) * D + r0 + tx] = tile[tx][ty + i];
}

// =====================================================================
// x,z fp32 -> f16 (elementwise, vectorized)
// =====================================================================
__global__ __launch_bounds__(256) void cast_xz(
    const float* __restrict__ x, const float* __restrict__ z,
    f16* __restrict__ xh, f16* __restrict__ zh)
{
    const float* src = blockIdx.y ? z : x;
    f16* dst = blockIdx.y ? zh : xh;
    const size_t i = ((size_t)blockIdx.x * 256 + threadIdx.x) * 4;
    const float4 v = *(const float4*)(src + i);
    f16x4 u = { (f16)v.x, (f16)v.y, (f16)v.z, (f16)v.w };
    *(f16x4*)(dst + i) = u;
}

// =====================================================================
// NT GEMM, 128x128 tile, BK=32, 256 threads (4 waves, each 64x64),
// global_load_lds width-16 staging (m97 structure).
// MODE 0: QK proj  A=xh/zh f16, B=Wt, +bias, C f16 [M][N]
// MODE 3: V proj   same but C written TRANSPOSED per batch: Vt[b][n][t]
// MODE 1: S=QK^T   A=Qh[b], B=Kh[b]; triangular grid; packed f16 out,
//                  *1/32, diag-masked
// MODE 2: y=A@V    A=packed softmax probs, B=Vt[b]; K clipped causal;
//                  C fp32 out
// =====================================================================
template<int MODE>
__global__ __launch_bounds__(256) void gemm_nt(
    const f16* __restrict__ Ag_, const f16* __restrict__ Bg_,
    void* __restrict__ Cg_, const float* __restrict__ bias)
{
    __shared__ f16 As[128 * 32];
    __shared__ f16 Bs[128 * 32];

    int bx, by;
    const int bz = blockIdx.z;
    if (MODE == 1) {
        const int idx = blockIdx.x;
        by = (int)((sqrtf(8.0f * idx + 1.0f) - 1.0f) * 0.5f);
        while ((by + 1) * (by + 2) / 2 <= idx) ++by;
        while (by * (by + 1) / 2 > idx) --by;
        bx = idx - by * (by + 1) / 2;
    } else { bx = blockIdx.x; by = blockIdx.y; }

    const size_t bm0 = (size_t)by * 128, bn0 = (size_t)bx * 128;
    const f16* Abase; const f16* Bbase;
    int lda, ldb, K;
    if (MODE == 0 || MODE == 3) {
        Abase = Ag_ + bm0 * D;                       lda = D;
        Bbase = Bg_ + bn0 * D;                       ldb = D; K = D;
    } else if (MODE == 1) {
        Abase = Ag_ + (size_t)bz * T * D + bm0 * D;  lda = D;
        Bbase = Bg_ + (size_t)bz * T * D + bn0 * D;  ldb = D; K = D;
    } else {
        Abase = Ag_ + ((size_t)bz * NTRI + (size_t)by * (by + 1) / 2) * 16384;
        lda = 128;
        Bbase = Bg_ + (size_t)bz * D * T + bn0 * T;  ldb = T;
        K = (by + 1) * 128;
    }

    const int t    = threadIdx.x;
    const int lane = t & 63, wave = t >> 6;
    const int wr   = (wave >> 1) * 64, wc = (wave & 1) * 64;
    const int fr   = lane & 15, fo = (lane >> 4) * 8;
    const int srow = t >> 2;              // staging row (it*64 + srow)
    const int scol = (t & 3) * 8;         // staging col chunk (8 f16 = 16B)
    const int wub  = (t & 192) * 8;       // wave-uniform LDS chunk base (f16)

    f32x4 acc[4][4] = {};

    for (int k0 = 0; k0 < K; k0 += 32) {
        const f16* Ak;
        if (MODE == 2) Ak = Abase + (size_t)(k0 >> 7) * 16384 + (k0 & 127);
        else           Ak = Abase + k0;
        #pragma unroll
        for (int it = 0; it < 2; ++it)
            load_lds16(Ak + (size_t)(it * 64 + srow) * lda + scol,
                       As + it * 2048 + wub);
        #pragma unroll
        for (int it = 0; it < 2; ++it)
            load_lds16(Bbase + k0 + (size_t)(it * 64 + srow) * ldb + scol,
                       Bs + it * 2048 + wub);
        __syncthreads();

        f16x8 av[4], bv[4];
        #pragma unroll
        for (int i = 0; i < 4; ++i)
            av[i] = *(const f16x8*)&As[(wr + i * 16 + fr) * 32 + fo];
        #pragma unroll
        for (int j = 0; j < 4; ++j)
            bv[j] = *(const f16x8*)&Bs[(wc + j * 16 + fr) * 32 + fo];
        #pragma unroll
        for (int i = 0; i < 4; ++i)
            #pragma unroll
            for (int j = 0; j < 4; ++j)
                acc[i][j] = __builtin_amdgcn_mfma_f32_16x16x32_f16(av[i], bv[j], acc[i][j], 0, 0, 0);
        __syncthreads();
    }

    // ---- epilogue.  C/D map: col = lane&15, row = (lane>>4)*4 + reg ----
    const int cr = (lane >> 4) * 4, cc = lane & 15;
    if (MODE == 0) {
        f16* Cp = (f16*)Cg_;
        #pragma unroll
        for (int j = 0; j < 4; ++j) {
            const int col = (int)bn0 + wc + j * 16 + cc;
            const float bb = bias[col];
            #pragma unroll
            for (int i = 0; i < 4; ++i)
                #pragma unroll
                for (int g = 0; g < 4; ++g)
                    Cp[(bm0 + wr + i * 16 + cr + g) * D + col] = (f16)(acc[i][j][g] + bb);
        }
    } else if (MODE == 3) {
        f16* Vt = (f16*)Cg_;
        const int b  = (int)(bm0 >> 11);          // 2048 rows per batch
        const int r0 = (int)(bm0 & 2047);
        #pragma unroll
        for (int j = 0; j < 4; ++j) {
            const int col = (int)bn0 + wc + j * 16 + cc;
            const float bb = bias[col];
            #pragma unroll
            for (int i = 0; i < 4; ++i) {
                f16x4 pk = { (f16)(acc[i][j][0] + bb), (f16)(acc[i][j][1] + bb),
                             (f16)(acc[i][j][2] + bb), (f16)(acc[i][j][3] + bb) };
                *(f16x4*)&Vt[(size_t)b * D * T + (size_t)col * T + r0 + wr + i * 16 + cr] = pk;
            }
        }
    } else if (MODE == 1) {
        f16* Cp = (f16*)Cg_ + ((size_t)bz * NTRI + (size_t)by * (by + 1) / 2 + bx) * 16384;
        #pragma unroll
        for (int i = 0; i < 4; ++i)
            #pragma unroll
            for (int j = 0; j < 4; ++j)
                #pragma unroll
                for (int g = 0; g < 4; ++g) {
                    const int lr = wr + i * 16 + cr + g, lc = wc + j * 16 + cc;
                    const int gr = (int)bm0 + lr, gc = (int)bn0 + lc;
                    Cp[lr * 128 + lc] = (gc > gr) ? (f16)(-30000.0f)
                                                  : (f16)(acc[i][j][g] * 0.03125f);
                }
    } else {
        float* Cp = (float*)Cg_ + (size_t)bz * T * D;
        #pragma unroll
        for (int i = 0; i < 4; ++i)
            #pragma unroll
            for (int j = 0; j < 4; ++j)
                #pragma unroll
                for (int g = 0; g < 4; ++g)
                    Cp[(bm0 + wr + i * 16 + cr + g) * D + bn0 + wc + j * 16 + cc] = acc[i][j][g];
    }
}

// =====================================================================
// Row softmax over packed causal S (f16, in-place).
// One block per (row, batch); len = ceil128(r+1) values.
// =====================================================================
__global__ __launch_bounds__(256) void softmax_rows(f16* __restrict__ SA)
{
    const int r = blockIdx.x, b = blockIdx.y;
    const int ib  = r >> 7;
    const int len = (ib + 1) << 7;
    f16* base = SA + ((size_t)b * NTRI + (size_t)ib * (ib + 1) / 2) * 16384
                   + (size_t)(r & 127) * 128;
    const int t = threadIdx.x;

    float vals[8];
    float m = -3.4e38f;
    #pragma unroll
    for (int i = 0; i < 8; ++i) {
        const int j = t + i * 256;
        const float v = (j < len)
            ? (float)base[(size_t)(j >> 7) * 16384 + (j & 127)] : -3.4e38f;
        vals[i] = v;
        m = fmaxf(m, v);
    }
    #pragma unroll
    for (int o = 32; o > 0; o >>= 1) m = fmaxf(m, __shfl_xor(m, o, 64));
    __shared__ float red[4];
    if ((t & 63) == 0) red[t >> 6] = m;
    __syncthreads();
    m = fmaxf(fmaxf(red[0], red[1]), fmaxf(red[2], red[3]));
    __syncthreads();

    float s = 0.f;
    #pragma unroll
    for (int i = 0; i < 8; ++i) {
        const float e = __expf(vals[i] - m);
        vals[i] = e;
        s += e;
    }
    #pragma unroll
    for (int o = 32; o > 0; o >>= 1) s += __shfl_xor(s, o, 64);
    if ((t & 63) == 0) red[t >> 6] = s;
    __syncthreads();
    s = (red[0] + red[1]) + (red[2] + red[3]);
    const float rinv = 1.0f / s;

    #pragma unroll
    for (int i = 0; i < 8; ++i) {
        const int j = t + i * 256;
        if (j < len) base[(size_t)(j >> 7) * 16384 + (j & 127)] = (f16)(vals[i] * rinv);
    }
}

// =====================================================================
// launch
// =====================================================================
extern "C" void kernel_launch(void* const* d_in, const int* in_sizes, int n_in,
                              void* d_out, int out_size, void* d_ws, size_t ws_size,
                              hipStream_t stream)
{
    const float* x  = (const float*)d_in[0];
    const float* z  = (const float*)d_in[1];
    const float* Wq = (const float*)d_in[2];
    const float* bq = (const float*)d_in[3];
    const float* Wk = (const float*)d_in[4];
    const float* bk = (const float*)d_in[5];
    const float* Wv = (const float*)d_in[6];
    const float* bv = (const float*)d_in[7];
    // d_in[8] = mask: fixed causal lower-triangular, baked in.
    float* out = (float*)d_out;

    char* ws = (char*)d_ws;
    // ws layout (MiB): Wt 0-6 | xh 6-38 | zh 38-70 | Qh 70-102 |
    //                  Kh 102-134 | Vt 134-166 | SA 166-200   (200 MiB total)
    f16* Wt = (f16*)(ws);
    f16* xh = (f16*)(ws + 6291456ull);
    f16* zh = (f16*)(ws + 39845888ull);
    f16* Qh = (f16*)(ws + 73400320ull);
    f16* Kh = (f16*)(ws + 106954752ull);
    f16* Vt = (f16*)(ws + 140509184ull);
    f16* SA = (f16*)(ws + 174063616ull);

    cast_transpose_w<<<dim3(32, 32, 3), 256, 0, stream>>>(Wq, Wk, Wv, Wt);
    cast_xz<<<dim3(16384, 2, 1), 256, 0, stream>>>(x, z, xh, zh);
    gemm_nt<0><<<dim3(8, 128, 1), 256, 0, stream>>>(xh, Wt,           Qh, bq);
    gemm_nt<0><<<dim3(8, 128, 1), 256, 0, stream>>>(zh, Wt + 1048576, Kh, bk);
    gemm_nt<3><<<dim3(8, 128, 1), 256, 0, stream>>>(zh, Wt + 2097152, Vt, bv);
    gemm_nt<1><<<dim3(136, 1, 8), 256, 0, stream>>>(Qh, Kh, SA, nullptr);
    softmax_rows<<<dim3(2048, 8, 1), 256, 0, stream>>>(SA);
    gemm_nt<2><<<dim3(8, 16, 8), 256, 0, stream>>>(SA, Vt, out, nullptr);
}

// Round 3
// 500.233 us; speedup vs baseline: 1.3300x; 1.0690x over previous
//
#include <hip/hip_runtime.h>

// ---- types ----
typedef _Float16 f16;
typedef _Float16 f16x8 __attribute__((ext_vector_type(8)));
typedef _Float16 f16x4 __attribute__((ext_vector_type(4)));
typedef float    f32x4 __attribute__((ext_vector_type(4)));

// ---- problem constants ----
constexpr int NB   = 8;      // batch
constexpr int T    = 2048;   // Tx = Tz
constexpr int D    = 1024;   // Dx = Dz = Datt = Dout
constexpr int NTRI = 136;    // 16*17/2 causal 128x128 blocks per batch

// async global->LDS, 16B per lane; LDS dest = wave-uniform base + lane*16
__device__ __forceinline__ void load_lds16(const f16* g, f16* l) {
    __builtin_amdgcn_global_load_lds(
        (const __attribute__((address_space(1))) void*)g,
        (__attribute__((address_space(3))) void*)l, 16, 0, 0);
}

// =====================================================================
// Weight cast + transpose: W[k][n] fp32 -> Wt[n][k] f16   (3 matrices)
// =====================================================================
__global__ __launch_bounds__(256) void cast_transpose_w(
    const float* __restrict__ W0, const float* __restrict__ W1,
    const float* __restrict__ W2, f16* __restrict__ Wt)
{
    __shared__ f16 tile[32][33];
    const int which = blockIdx.z;
    const float* W = which == 0 ? W0 : (which == 1 ? W1 : W2);
    f16* dst = Wt + (size_t)which * D * D;
    const int c0 = blockIdx.x * 32, r0 = blockIdx.y * 32;
    const int tx = threadIdx.x & 31, ty = threadIdx.x >> 5;
    #pragma unroll
    for (int i = 0; i < 32; i += 8)
        tile[ty + i][tx] = (f16)W[(size_t)(r0 + ty + i) * D + c0 + tx];
    __syncthreads();
    #pragma unroll
    for (int i = 0; i < 32; i += 8)
        dst[(size_t)(c0 + ty + i) * D + r0 + tx] = tile[tx][ty + i];
}

// =====================================================================
// x,z fp32 -> f16 (elementwise, vectorized)
// =====================================================================
__global__ __launch_bounds__(256) void cast_xz(
    const float* __restrict__ x, const float* __restrict__ z,
    f16* __restrict__ xh, f16* __restrict__ zh)
{
    const float* src = blockIdx.y ? z : x;
    f16* dst = blockIdx.y ? zh : xh;
    const size_t i = ((size_t)blockIdx.x * 256 + threadIdx.x) * 4;
    const float4 v = *(const float4*)(src + i);
    f16x4 u = { (f16)v.x, (f16)v.y, (f16)v.z, (f16)v.w };
    *(f16x4*)(dst + i) = u;
}

// =====================================================================
// NT GEMM, 128x128 tile, BK=64 (two 32-wide LDS panels per barrier),
// 256 threads (4 waves, each 64x64), global_load_lds width-16 staging.
// MODE 0: Q proj   A=xh, B=Wt(q), +bq, C f16 [M][N]
// MODE 4: KV proj  A=zh, B=[Wk|Wv]t; bx<8 -> Kh normal; bx>=8 -> Vt
//                  transposed per batch
// MODE 1: S        A=Qh[b], B=Kh[b]; triangular grid; writes UNNORMALIZED
//                  p=exp(S/32) f16 packed (masked->0) + fp32 row sums
//                  via atomics into rsum
// MODE 2: y=P@V/r  A=packed p, B=Vt[b]; K clipped causal, by descending;
//                  epilogue scales by 1/rsum; C fp32
// =====================================================================
template<int MODE>
__global__ __launch_bounds__(256) void gemm_nt(
    const f16* __restrict__ Ag_, const f16* __restrict__ Bg_,
    void* __restrict__ Cg_, void* __restrict__ Cg2_,
    const float* __restrict__ bias, const float* __restrict__ bias2,
    float* __restrict__ rsum)
{
    __shared__ f16 As[2 * 128 * 32];
    __shared__ f16 Bs[2 * 128 * 32];

    int bx, by;
    const int bz = blockIdx.z;
    if (MODE == 1) {
        const int idx = blockIdx.x;
        by = (int)((sqrtf(8.0f * idx + 1.0f) - 1.0f) * 0.5f);
        while ((by + 1) * (by + 2) / 2 <= idx) ++by;
        while (by * (by + 1) / 2 > idx) --by;
        bx = idx - by * (by + 1) / 2;
    } else if (MODE == 2) {
        bx = blockIdx.x; by = 15 - blockIdx.y;   // long-K blocks first
    } else {
        bx = blockIdx.x; by = blockIdx.y;
    }

    const size_t bm0 = (size_t)by * 128, bn0 = (size_t)bx * 128;
    const f16* Abase; const f16* Bbase;
    int lda, ldb, K;
    if (MODE == 0 || MODE == 4) {
        Abase = Ag_ + bm0 * D;                       lda = D;
        Bbase = Bg_ + bn0 * D;                       ldb = D; K = D;
    } else if (MODE == 1) {
        Abase = Ag_ + (size_t)bz * T * D + bm0 * D;  lda = D;
        Bbase = Bg_ + (size_t)bz * T * D + bn0 * D;  ldb = D; K = D;
    } else {
        Abase = Ag_ + ((size_t)bz * NTRI + (size_t)by * (by + 1) / 2) * 16384;
        lda = 128;
        Bbase = Bg_ + (size_t)bz * D * T + bn0 * T;  ldb = T;
        K = (by + 1) * 128;
    }

    const int t    = threadIdx.x;
    const int lane = t & 63, wave = t >> 6;
    const int wr   = (wave >> 1) * 64, wc = (wave & 1) * 64;
    const int fr   = lane & 15, fo = (lane >> 4) * 8;
    const int srow = t >> 2;              // staging row within 64-row half
    const int scol = (t & 3) * 8;         // staging col chunk (8 f16 = 16B)
    const int wub  = (t & 192) * 8;       // wave-uniform LDS chunk base (f16)

    f32x4 acc[4][4] = {};

    for (int k0 = 0; k0 < K; k0 += 64) {
        #pragma unroll
        for (int p = 0; p < 2; ++p) {
            const int k = k0 + p * 32;
            const f16* Ak;
            if (MODE == 2) Ak = Abase + (size_t)(k >> 7) * 16384 + (k & 127);
            else           Ak = Abase + k;
            #pragma unroll
            for (int it = 0; it < 2; ++it)
                load_lds16(Ak + (size_t)(it * 64 + srow) * lda + scol,
                           As + p * 4096 + it * 2048 + wub);
            #pragma unroll
            for (int it = 0; it < 2; ++it)
                load_lds16(Bbase + k + (size_t)(it * 64 + srow) * ldb + scol,
                           Bs + p * 4096 + it * 2048 + wub);
        }
        __syncthreads();

        #pragma unroll
        for (int p = 0; p < 2; ++p) {
            f16x8 av[4], bv[4];
            #pragma unroll
            for (int i = 0; i < 4; ++i)
                av[i] = *(const f16x8*)&As[p * 4096 + (wr + i * 16 + fr) * 32 + fo];
            #pragma unroll
            for (int j = 0; j < 4; ++j)
                bv[j] = *(const f16x8*)&Bs[p * 4096 + (wc + j * 16 + fr) * 32 + fo];
            #pragma unroll
            for (int i = 0; i < 4; ++i)
                #pragma unroll
                for (int j = 0; j < 4; ++j)
                    acc[i][j] = __builtin_amdgcn_mfma_f32_16x16x32_f16(av[i], bv[j], acc[i][j], 0, 0, 0);
        }
        __syncthreads();
    }

    // ---- epilogue.  C/D map: col = lane&15, row = (lane>>4)*4 + reg ----
    const int cr = (lane >> 4) * 4, cc = lane & 15;
    if (MODE == 0) {
        f16* Cp = (f16*)Cg_;
        #pragma unroll
        for (int j = 0; j < 4; ++j) {
            const int col = (int)bn0 + wc + j * 16 + cc;
            const float bb = bias[col];
            #pragma unroll
            for (int i = 0; i < 4; ++i)
                #pragma unroll
                for (int g = 0; g < 4; ++g)
                    Cp[(bm0 + wr + i * 16 + cr + g) * D + col] = (f16)(acc[i][j][g] + bb);
        }
    } else if (MODE == 4) {
        if (bx < 8) {
            f16* Cp = (f16*)Cg_;
            #pragma unroll
            for (int j = 0; j < 4; ++j) {
                const int col = (int)bn0 + wc + j * 16 + cc;
                const float bb = bias[col];
                #pragma unroll
                for (int i = 0; i < 4; ++i)
                    #pragma unroll
                    for (int g = 0; g < 4; ++g)
                        Cp[(bm0 + wr + i * 16 + cr + g) * D + col] = (f16)(acc[i][j][g] + bb);
            }
        } else {
            f16* Vt = (f16*)Cg2_;
            const int b  = (int)(bm0 >> 11);
            const int r0 = (int)(bm0 & 2047);
            #pragma unroll
            for (int j = 0; j < 4; ++j) {
                const int colv = (int)bn0 - 1024 + wc + j * 16 + cc;
                const float bb = bias2[colv];
                #pragma unroll
                for (int i = 0; i < 4; ++i) {
                    f16x4 pk = { (f16)(acc[i][j][0] + bb), (f16)(acc[i][j][1] + bb),
                                 (f16)(acc[i][j][2] + bb), (f16)(acc[i][j][3] + bb) };
                    *(f16x4*)&Vt[(size_t)b * D * T + (size_t)colv * T + r0 + wr + i * 16 + cr] = pk;
                }
            }
        }
    } else if (MODE == 1) {
        f16* Cp = (f16*)Cg_ + ((size_t)bz * NTRI + (size_t)by * (by + 1) / 2 + bx) * 16384;
        float* rs = rsum + (size_t)bz * T + bm0;
        float rowsum[4][4] = {};   // [i][g]
        #pragma unroll
        for (int i = 0; i < 4; ++i)
            #pragma unroll
            for (int j = 0; j < 4; ++j)
                #pragma unroll
                for (int g = 0; g < 4; ++g) {
                    const int lr = wr + i * 16 + cr + g, lc = wc + j * 16 + cc;
                    const int r = (int)bm0 + lr, c = (int)bn0 + lc;
                    const float p = (c > r) ? 0.0f : __expf(acc[i][j][g] * 0.03125f);
                    Cp[lr * 128 + lc] = (f16)p;
                    rowsum[i][g] += p;
                }
        // reduce across the 16 lanes holding this row's columns
        #pragma unroll
        for (int i = 0; i < 4; ++i)
            #pragma unroll
            for (int g = 0; g < 4; ++g) {
                float s = rowsum[i][g];
                s += __shfl_xor(s, 1, 64);
                s += __shfl_xor(s, 2, 64);
                s += __shfl_xor(s, 4, 64);
                s += __shfl_xor(s, 8, 64);
                if (cc == 0) atomicAdd(&rs[wr + i * 16 + cr + g], s);
            }
    } else {
        float* Cp = (float*)Cg_ + (size_t)bz * T * D;
        const float* rs = rsum + (size_t)bz * T;
        #pragma unroll
        for (int i = 0; i < 4; ++i) {
            const int r4 = (int)bm0 + wr + i * 16 + cr;
            float rinv[4];
            #pragma unroll
            for (int g = 0; g < 4; ++g) rinv[g] = 1.0f / rs[r4 + g];
            #pragma unroll
            for (int j = 0; j < 4; ++j)
                #pragma unroll
                for (int g = 0; g < 4; ++g)
                    Cp[(size_t)(r4 + g) * D + bn0 + wc + j * 16 + cc] = acc[i][j][g] * rinv[g];
        }
    }
}

// =====================================================================
// launch
// =====================================================================
extern "C" void kernel_launch(void* const* d_in, const int* in_sizes, int n_in,
                              void* d_out, int out_size, void* d_ws, size_t ws_size,
                              hipStream_t stream)
{
    const float* x  = (const float*)d_in[0];
    const float* z  = (const float*)d_in[1];
    const float* Wq = (const float*)d_in[2];
    const float* bq = (const float*)d_in[3];
    const float* Wk = (const float*)d_in[4];
    const float* bk = (const float*)d_in[5];
    const float* Wv = (const float*)d_in[6];
    const float* bv = (const float*)d_in[7];
    // d_in[8] = mask: fixed causal lower-triangular, baked in.
    float* out = (float*)d_out;

    char* ws = (char*)d_ws;
    // ws layout (MiB): Wt 0-6 | xh 6-38 | zh 38-70 | Qh 70-102 |
    //                  Kh 102-134 | Vt 134-166 | SA 166-200 | rsum 200+
    f16*   Wt   = (f16*)(ws);
    f16*   xh   = (f16*)(ws + 6291456ull);
    f16*   zh   = (f16*)(ws + 39845888ull);
    f16*   Qh   = (f16*)(ws + 73400320ull);
    f16*   Kh   = (f16*)(ws + 106954752ull);
    f16*   Vt   = (f16*)(ws + 140509184ull);
    f16*   SA   = (f16*)(ws + 174063616ull);
    float* rsum = (float*)(ws + 209715200ull);

    hipMemsetAsync(rsum, 0, (size_t)NB * T * sizeof(float), stream);
    cast_transpose_w<<<dim3(32, 32, 3), 256, 0, stream>>>(Wq, Wk, Wv, Wt);
    cast_xz<<<dim3(16384, 2, 1), 256, 0, stream>>>(x, z, xh, zh);
    gemm_nt<0><<<dim3(8, 128, 1), 256, 0, stream>>>(xh, Wt, Qh, nullptr, bq, nullptr, nullptr);
    gemm_nt<4><<<dim3(16, 128, 1), 256, 0, stream>>>(zh, Wt + 1048576, Kh, Vt, bk, bv, nullptr);
    gemm_nt<1><<<dim3(136, 1, 8), 256, 0, stream>>>(Qh, Kh, SA, nullptr, nullptr, nullptr, rsum);
    gemm_nt<2><<<dim3(8, 16, 8), 256, 0, stream>>>(SA, Vt, out, nullptr, nullptr, nullptr, rsum);
}